// Round 4
// baseline (698.008 us; speedup 1.0000x reference)
//
#include <hip/hip_runtime.h>
#include <hip/hip_bf16.h>
#include <math.h>

#define NN 100000
#define EE 1600000
#define IN_F 128
#define HH 4
#define DD 32
#define LL 3
#define NB_ 391          // node buckets of 256: ceil(N/256)
#define EPB 4096         // edges per block in bucket hist/partition

typedef __bf16 bf16x8 __attribute__((ext_vector_type(8)));
typedef float f32x4 __attribute__((ext_vector_type(4)));

static __device__ __forceinline__ unsigned short f2bf(float x) {
    __hip_bfloat16 b = __float2bfloat16(x);
    return *reinterpret_cast<unsigned short*>(&b);
}

// ---------------------------------------------------------------------------
// fp32 -> bf16 convert for the initial node features
// ---------------------------------------------------------------------------
__global__ void convert_h_kernel(const float* __restrict__ x,
                                 unsigned short* __restrict__ xb) {
    const int i = blockIdx.x * blockDim.x + threadIdx.x;   // over N*128/4
    if (i >= NN * 32) return;
    const float4 v = ((const float4*)x)[i];
    ushort4 o;
    o.x = f2bf(v.x); o.y = f2bf(v.y); o.z = f2bf(v.z); o.w = f2bf(v.w);
    ((ushort4*)xb)[i] = o;
}

// W [l][k][n] fp32 -> wt [l][n][k] bf16 (B-operand layout for MFMA)
__global__ void wt_kernel(const float* __restrict__ Ws,
                          unsigned short* __restrict__ wt) {
    const int i = blockIdx.x * blockDim.x + threadIdx.x;   // L*128*128
    if (i >= LL * IN_F * IN_F) return;
    const int l = i >> 14, r = i & 16383;
    const int n = r >> 7, k = r & 127;
    wt[i] = f2bf(Ws[(l << 14) + k * IN_F + n]);
}

// ---------------------------------------------------------------------------
// MFMA GEMM: ft = x @ W (bf16 in, fp32 acc), fused el/er dots from fp32 acc.
// ---------------------------------------------------------------------------
__global__ __launch_bounds__(256) void gemm_mfma_kernel(
    const unsigned short* __restrict__ x_bf,
    const unsigned short* __restrict__ wt,    // [128 n][128 k] bf16
    const float* __restrict__ al,
    const float* __restrict__ ar,
    unsigned short* __restrict__ ft_bf,
    float* __restrict__ el,
    float* __restrict__ er) {
    const int wave = (blockIdx.x * blockDim.x + threadIdx.x) >> 6;
    const int lane = threadIdx.x & 63;
    const int base = wave * 16;
    if (base >= NN) return;
    const int c = lane & 15;
    const int quad = lane >> 4;

    const int arow = min(base + c, NN - 1);
    const bf16x8* ap = (const bf16x8*)(x_bf + (size_t)arow * IN_F);
    bf16x8 a[4];
#pragma unroll
    for (int kc = 0; kc < 4; ++kc) a[kc] = ap[kc * 4 + quad];

    f32x4 acc[8];
#pragma unroll
    for (int nt = 0; nt < 8; ++nt) {
        const bf16x8* bp = (const bf16x8*)(wt + (size_t)(nt * 16 + c) * IN_F);
        f32x4 d = {0.f, 0.f, 0.f, 0.f};
#pragma unroll
        for (int kc = 0; kc < 4; ++kc)
            d = __builtin_amdgcn_mfma_f32_16x16x32_bf16(a[kc], bp[kc * 4 + quad], d, 0, 0, 0);
        acc[nt] = d;
    }

    // ft store (bf16)
#pragma unroll
    for (int r = 0; r < 4; ++r) {
        const int n = base + quad * 4 + r;
        if (n < NN) {
#pragma unroll
            for (int nt = 0; nt < 8; ++nt)
                ft_bf[(size_t)n * IN_F + nt * 16 + c] = f2bf(acc[nt][r]);
        }
    }

    // attention dots from fp32 acc: head h covers tiles 2h, 2h+1
#pragma unroll
    for (int h = 0; h < 4; ++h) {
        float pl[4], pr[4];
#pragma unroll
        for (int r = 0; r < 4; ++r) {
            const float a0 = acc[2 * h][r], a1 = acc[2 * h + 1][r];
            pl[r] = a0 * al[h * 32 + c] + a1 * al[h * 32 + 16 + c];
            pr[r] = a0 * ar[h * 32 + c] + a1 * ar[h * 32 + 16 + c];
        }
#pragma unroll
        for (int off = 8; off >= 1; off >>= 1) {
#pragma unroll
            for (int r = 0; r < 4; ++r) {
                pl[r] += __shfl_xor(pl[r], off);
                pr[r] += __shfl_xor(pr[r], off);
            }
        }
        if (c == 0) {
#pragma unroll
            for (int r = 0; r < 4; ++r) {
                const int n = base + quad * 4 + r;
                if (n < NN) {
                    el[n * HH + h] = pl[r];
                    er[n * HH + h] = pr[r];
                }
            }
        }
    }
}

// ---------------------------------------------------------------------------
// CSR build, two-pass bucket radix by dst>>8 (391 buckets of 256 nodes).
// ---------------------------------------------------------------------------

// per-block LDS histogram of bucket ids -> global bucket totals
__global__ void bucket_hist_kernel(const int* __restrict__ dst,
                                   int* __restrict__ tot) {
    __shared__ int l[NB_];
    for (int b = threadIdx.x; b < NB_; b += 256) l[b] = 0;
    __syncthreads();
    const int e0 = blockIdx.x * EPB;
    const int e1 = min(e0 + EPB, EE);
    for (int e = e0 + threadIdx.x; e < e1; e += 256)
        atomicAdd(&l[dst[e] >> 8], 1);
    __syncthreads();
    for (int b = threadIdx.x; b < NB_; b += 256)
        if (l[b]) atomicAdd(&tot[b], l[b]);
}

// exclusive scan of 391 bucket totals; writes base (NB_+1) and cursor copy
__global__ void bucket_scan_kernel(const int* __restrict__ tot,
                                   int* __restrict__ base,
                                   int* __restrict__ cur) {
    __shared__ int tmp[512];
    const int tid = threadIdx.x;
    int v = (tid < NB_) ? tot[tid] : 0;
    tmp[tid] = v;
    __syncthreads();
    for (int off = 1; off < 512; off <<= 1) {
        int t = (tid >= off) ? tmp[tid - off] : 0;
        __syncthreads();
        if (tid >= off) tmp[tid] += t;
        __syncthreads();
    }
    if (tid < NB_) {
        const int excl = tmp[tid] - v;
        base[tid] = excl;
        cur[tid] = excl;
    }
    if (tid == 0) base[NB_] = EE;
}

// partition edges into buckets: one atomic per (block,bucket) to reserve a
// range, then append packed (dstLow<<17 | src).
__global__ void partition_kernel(const int* __restrict__ src,
                                 const int* __restrict__ dst,
                                 int* __restrict__ cur,
                                 int* __restrict__ bkt) {
    __shared__ int lcnt[NB_];
    __shared__ int lbase[NB_];
    const int tid = threadIdx.x;
    const int e0 = blockIdx.x * EPB;
    const int e1 = min(e0 + EPB, EE);
    for (int b = tid; b < NB_; b += 256) lcnt[b] = 0;
    __syncthreads();
    for (int e = e0 + tid; e < e1; e += 256)
        atomicAdd(&lcnt[dst[e] >> 8], 1);
    __syncthreads();
    for (int b = tid; b < NB_; b += 256) {
        const int c = lcnt[b];
        lbase[b] = c ? atomicAdd(&cur[b], c) : 0;
        lcnt[b] = 0;
    }
    __syncthreads();
    for (int e = e0 + tid; e < e1; e += 256) {
        const int d = dst[e];
        const int b = d >> 8;
        const int idx = atomicAdd(&lcnt[b], 1);
        bkt[lbase[b] + idx] = ((d & 255) << 17) | src[e];
    }
}

// within-bucket sort: LDS count+scan over 256 local nodes emits cnt[] and
// row_start[] directly; final ssrc scatter lands in a contiguous window.
// Post-pass: per-node insertion sort by src so the aggregate's gathers sweep
// src-space monotonically (concurrent waves share a ~2-4 MB moving window of
// ft -> per-XCD L2 hits instead of random misses over the 25.6 MB table).
__global__ void bucket_sort_kernel(int* __restrict__ bkt,
                                   const int* __restrict__ base,
                                   int* __restrict__ cnt,
                                   int* __restrict__ row_start,
                                   int* __restrict__ ssrc) {
    __shared__ int lcnt[256];
    __shared__ int loff[256];
    const int tid = threadIdx.x;
    const int b = blockIdx.x;
    const int s0 = base[b], s1 = base[b + 1];
    lcnt[tid] = 0;
    __syncthreads();
    for (int p = s0 + tid; p < s1; p += 256)
        atomicAdd(&lcnt[bkt[p] >> 17], 1);
    __syncthreads();
    const int v = lcnt[tid];
    loff[tid] = v;
    __syncthreads();
    for (int off = 1; off < 256; off <<= 1) {
        int t = (tid >= off) ? loff[tid - off] : 0;
        __syncthreads();
        if (tid >= off) loff[tid] += t;
        __syncthreads();
    }
    const int excl = loff[tid] - v;          // exclusive local offset
    const int n = b * 256 + tid;
    if (n < NN) {
        cnt[n] = v;
        row_start[n] = s0 + excl;
    }
    __syncthreads();
    loff[tid] = excl;
    lcnt[tid] = 0;
    __syncthreads();
    for (int p = s0 + tid; p < s1; p += 256) {
        const int w = bkt[p];
        const int dl = w >> 17;
        const int idx = atomicAdd(&lcnt[dl], 1);
        ssrc[s0 + loff[dl] + idx] = w & 0x1FFFF;
    }
    // all of this block's ssrc window written (same CU; __syncthreads drains
    // vmcnt); now sort each node's contiguous ~deg-entry window (L1-hot).
    __syncthreads();
    const int beg2 = s0 + excl;
    for (int i2 = beg2 + 1; i2 < beg2 + v; ++i2) {
        const int key = ssrc[i2];
        int j2 = i2 - 1;
        while (j2 >= beg2 && ssrc[j2] > key) { ssrc[j2 + 1] = ssrc[j2]; --j2; }
        ssrc[j2 + 1] = key;
    }
}

// ---------------------------------------------------------------------------
// Fused aggregation: one wave per dst node; the two wave halves process two
// edges of the SAME node concurrently, each lane covering 4 features via
// dwordx2 gathers.  Main loop unrolled to 8 edges (4 row-gathers in flight
// per half) to cover L2-miss latency; edge lists are src-sorted for L2
// sweep locality.
// ---------------------------------------------------------------------------
__global__ void aggregate_kernel(const unsigned int* __restrict__ ftw,
                                 const float* __restrict__ el,
                                 const float* __restrict__ er,
                                 const float* __restrict__ xin,
                                 const float* __restrict__ bias,
                                 const int* __restrict__ row_start,
                                 const int* __restrict__ cnt,
                                 const int* __restrict__ ssrc,
                                 float* __restrict__ out,
                                 unsigned short* __restrict__ out_bf,
                                 float* __restrict__ den_arr) {
    const int n = (blockIdx.x * blockDim.x + threadIdx.x) >> 6;
    const int lane = threadIdx.x & 63;
    if (n >= NN) return;
    const int half = lane >> 5;          // 0: even edges, 1: odd edges
    const int l31 = lane & 31;           // features 4*l31 .. 4*l31+3
    const int h = l31 >> 3;              // head

    const float ern = er[n * HH + h];
    const int beg = row_start[n];
    const int end = beg + cnt[n];

    float acc0 = 0.f, acc1 = 0.f, acc2 = 0.f, acc3 = 0.f, den = 0.f;
    const uint2* ft2 = (const uint2*)ftw;   // row = 32 x uint2 (128 bf16)

    int p = beg;
    for (; p + 8 <= end; p += 8) {
        const int sA = ssrc[p + half];
        const int sB = ssrc[p + 2 + half];
        const int sC = ssrc[p + 4 + half];
        const int sD = ssrc[p + 6 + half];
        float evA = el[sA * HH + h] + ern;
        float evB = el[sB * HH + h] + ern;
        float evC = el[sC * HH + h] + ern;
        float evD = el[sD * HH + h] + ern;
        const uint2 wA = ft2[(size_t)sA * 32 + l31];
        const uint2 wB = ft2[(size_t)sB * 32 + l31];
        const uint2 wC = ft2[(size_t)sC * 32 + l31];
        const uint2 wD = ft2[(size_t)sD * 32 + l31];
        evA = evA > 0.f ? evA : 0.2f * evA;
        evB = evB > 0.f ? evB : 0.2f * evB;
        evC = evC > 0.f ? evC : 0.2f * evC;
        evD = evD > 0.f ? evD : 0.2f * evD;
        const float eA = __expf(evA);
        const float eB = __expf(evB);
        const float eC = __expf(evC);
        const float eD = __expf(evD);
        den += (eA + eB) + (eC + eD);
        acc0 = fmaf(eA, __uint_as_float(wA.x << 16), acc0);
        acc1 = fmaf(eA, __uint_as_float(wA.x & 0xffff0000u), acc1);
        acc2 = fmaf(eA, __uint_as_float(wA.y << 16), acc2);
        acc3 = fmaf(eA, __uint_as_float(wA.y & 0xffff0000u), acc3);
        acc0 = fmaf(eB, __uint_as_float(wB.x << 16), acc0);
        acc1 = fmaf(eB, __uint_as_float(wB.x & 0xffff0000u), acc1);
        acc2 = fmaf(eB, __uint_as_float(wB.y << 16), acc2);
        acc3 = fmaf(eB, __uint_as_float(wB.y & 0xffff0000u), acc3);
        acc0 = fmaf(eC, __uint_as_float(wC.x << 16), acc0);
        acc1 = fmaf(eC, __uint_as_float(wC.x & 0xffff0000u), acc1);
        acc2 = fmaf(eC, __uint_as_float(wC.y << 16), acc2);
        acc3 = fmaf(eC, __uint_as_float(wC.y & 0xffff0000u), acc3);
        acc0 = fmaf(eD, __uint_as_float(wD.x << 16), acc0);
        acc1 = fmaf(eD, __uint_as_float(wD.x & 0xffff0000u), acc1);
        acc2 = fmaf(eD, __uint_as_float(wD.y << 16), acc2);
        acc3 = fmaf(eD, __uint_as_float(wD.y & 0xffff0000u), acc3);
    }
    for (; p + 4 <= end; p += 4) {
        const int sA = ssrc[p + half];
        const int sB = ssrc[p + 2 + half];
        float evA = el[sA * HH + h] + ern;
        float evB = el[sB * HH + h] + ern;
        const uint2 wA = ft2[(size_t)sA * 32 + l31];
        const uint2 wB = ft2[(size_t)sB * 32 + l31];
        evA = evA > 0.f ? evA : 0.2f * evA;
        evB = evB > 0.f ? evB : 0.2f * evB;
        const float eA = __expf(evA);
        const float eB = __expf(evB);
        den += eA + eB;
        acc0 = fmaf(eA, __uint_as_float(wA.x << 16), acc0);
        acc1 = fmaf(eA, __uint_as_float(wA.x & 0xffff0000u), acc1);
        acc2 = fmaf(eA, __uint_as_float(wA.y << 16), acc2);
        acc3 = fmaf(eA, __uint_as_float(wA.y & 0xffff0000u), acc3);
        acc0 = fmaf(eB, __uint_as_float(wB.x << 16), acc0);
        acc1 = fmaf(eB, __uint_as_float(wB.x & 0xffff0000u), acc1);
        acc2 = fmaf(eB, __uint_as_float(wB.y << 16), acc2);
        acc3 = fmaf(eB, __uint_as_float(wB.y & 0xffff0000u), acc3);
    }
    for (; p < end; p += 2) {
        const bool valid = (p + half) < end;
        // invalid lanes replay a valid row (beg < end here) with ee=0 so no
        // garbage bf16 bits (possible inf/nan) enter an fma.
        const int s = ssrc[valid ? p + half : beg];
        float ev = el[s * HH + h] + ern;
        const uint2 w = ft2[(size_t)s * 32 + l31];
        ev = ev > 0.f ? ev : 0.2f * ev;
        const float e1 = valid ? __expf(ev) : 0.f;
        den += e1;
        acc0 = fmaf(e1, __uint_as_float(w.x << 16), acc0);
        acc1 = fmaf(e1, __uint_as_float(w.x & 0xffff0000u), acc1);
        acc2 = fmaf(e1, __uint_as_float(w.y << 16), acc2);
        acc3 = fmaf(e1, __uint_as_float(w.y & 0xffff0000u), acc3);
    }

    // combine the two halves
    den  += __shfl_xor(den, 32);
    acc0 += __shfl_xor(acc0, 32);
    acc1 += __shfl_xor(acc1, 32);
    acc2 += __shfl_xor(acc2, 32);
    acc3 += __shfl_xor(acc3, 32);

    if (lane < 32) {
        if ((l31 & 7) == 0) den_arr[n * HH + h] = den;
        const float inv = 1.f / fmaxf(den, 1e-9f);
        const float4 xi = ((const float4*)xin)[(size_t)n * 32 + l31];
        const float4 bb = ((const float4*)bias)[l31];
        float v0 = acc0 * inv + xi.x + bb.x;
        float v1 = acc1 * inv + xi.y + bb.y;
        float v2 = acc2 * inv + xi.z + bb.z;
        float v3 = acc3 * inv + xi.w + bb.w;
        v0 = v0 > 0.f ? v0 : __expf(v0) - 1.f;
        v1 = v1 > 0.f ? v1 : __expf(v1) - 1.f;
        v2 = v2 > 0.f ? v2 : __expf(v2) - 1.f;
        v3 = v3 > 0.f ? v3 : __expf(v3) - 1.f;
        ((float4*)out)[(size_t)n * 32 + l31] = make_float4(v0, v1, v2, v3);
        ushort4 ob;
        ob.x = f2bf(v0); ob.y = f2bf(v1); ob.z = f2bf(v2); ob.w = f2bf(v3);
        ((ushort4*)out_bf)[(size_t)n * 32 + l31] = ob;
    }
}

// ---------------------------------------------------------------------------
// a[e,h] = exp(leaky(el[src]+er[dst])) / den[dst]  (bit-identical __expf)
// ---------------------------------------------------------------------------
__global__ void attn_out_kernel(const int* __restrict__ src,
                                const int* __restrict__ dst,
                                const float* __restrict__ el,
                                const float* __restrict__ er,
                                const float* __restrict__ den,
                                float* __restrict__ a_out) {
    const int e = blockIdx.x * blockDim.x + threadIdx.x;
    if (e >= EE) return;
    const int s = src[e], d = dst[e];
    const float4 l4 = ((const float4*)el)[s];
    const float4 r4 = ((const float4*)er)[d];
    const float4 dn = ((const float4*)den)[d];
    float v[4] = {l4.x + r4.x, l4.y + r4.y, l4.z + r4.z, l4.w + r4.w};
    float dv[4] = {dn.x, dn.y, dn.z, dn.w};
    float4 o;
    float* op = &o.x;
#pragma unroll
    for (int hh = 0; hh < 4; ++hh) {
        float t = v[hh] > 0.f ? v[hh] : 0.2f * v[hh];
        op[hh] = __expf(t) / fmaxf(dv[hh], 1e-9f);
    }
    ((float4*)a_out)[e] = o;
}

extern "C" void kernel_launch(void* const* d_in, const int* in_sizes, int n_in,
                              void* d_out, int out_size, void* d_ws, size_t ws_size,
                              hipStream_t stream) {
    const float* h    = (const float*)d_in[0];
    const int*   src  = (const int*)  d_in[1];
    const int*   dst  = (const int*)  d_in[2];
    const float* Ws   = (const float*)d_in[3];
    const float* al   = (const float*)d_in[4];
    const float* ar   = (const float*)d_in[5];
    const float* bias = (const float*)d_in[6];

    float* out_x = (float*)d_out;                         // [N,128] fp32
    float* out_a = out_x + (size_t)NN * IN_F;             // [E,4] fp32
    // x_bf (N*128 bf16 = 25.6 MB) aliases the out_a region (E*4 f32 = 25.6 MB):
    // needed only during the layer loop; attn_out overwrites it at the end.
    unsigned short* x_bf = (unsigned short*)out_a;

    char* ws = (char*)d_ws;
    unsigned short* ft_bf = (unsigned short*)ws;              // N*128 bf16
    float* bufA = (float*)(ft_bf + (size_t)NN * IN_F);        // N*128 f32
    float* el   = bufA + (size_t)NN * IN_F;                   // N*4
    float* er   = el + (size_t)NN * HH;                       // N*4
    float* den  = er + (size_t)NN * HH;                       // N*4
    int*   cnt        = (int*)(den + (size_t)NN * HH);        // N
    int*   row_start  = cnt + NN;                             // N
    int*   bucket_tot = row_start + NN;                       // 512 (NB_ used)
    int*   bucket_base= bucket_tot + 512;                     // 512 (NB_+1 used)
    int*   bucket_cur = bucket_base + 512;                    // 512 (NB_ used)
    int*   ssrc       = bucket_cur + 512;                     // E
    unsigned short* wt = (unsigned short*)(ssrc + EE);        // 3*128*128 bf16
    // bkt (E ints, CSR-build scratch only) aliases bufA: bufA is first
    // written by layer-0 aggregate, strictly after bucket_sort has consumed bkt.
    int* bkt = (int*)bufA;

    // ---- one-time conversions + CSR build (identical every call) ----
    convert_h_kernel<<<(NN * 32 + 255) / 256, 256, 0, stream>>>(h, x_bf);
    wt_kernel<<<(LL * IN_F * IN_F + 255) / 256, 256, 0, stream>>>(Ws, wt);

    hipMemsetAsync(bucket_tot, 0, 512 * sizeof(int), stream);
    const int ebks = (EE + EPB - 1) / EPB;   // 391
    bucket_hist_kernel<<<ebks, 256, 0, stream>>>(dst, bucket_tot);
    bucket_scan_kernel<<<1, 512, 0, stream>>>(bucket_tot, bucket_base, bucket_cur);
    partition_kernel<<<ebks, 256, 0, stream>>>(src, dst, bucket_cur, bkt);
    bucket_sort_kernel<<<NB_, 256, 0, stream>>>(bkt, bucket_base, cnt, row_start, ssrc);

    // layer schedule: L0: h->bufA, L1: bufA->out_x, L2: out_x->out_x
    const float* xin[LL]  = {h, bufA, out_x};
    float*       xout[LL] = {bufA, out_x, out_x};
    const int gemm_blocks = ((NN + 15) / 16 + 3) / 4;   // waves of 16 nodes, 4/block

    for (int i = 0; i < LL; ++i) {
        const float* all_ = al + (size_t)i * HH * DD;
        const float* arl = ar + (size_t)i * HH * DD;
        const float* bl  = bias + (size_t)i * HH * DD;

        gemm_mfma_kernel<<<gemm_blocks, 256, 0, stream>>>(
            x_bf, wt + (size_t)i * IN_F * IN_F, all_, arl, ft_bf, el, er);
        aggregate_kernel<<<(NN + 3) / 4, 256, 0, stream>>>(
            (const unsigned int*)ft_bf, el, er, xin[i], bl, row_start, cnt, ssrc,
            xout[i], x_bf, den);
    }
    attn_out_kernel<<<(EE + 255) / 256, 256, 0, stream>>>(src, dst, el, er, den, out_a);
}

// Round 5
// 580.665 us; speedup vs baseline: 1.2021x; 1.2021x over previous
//
#include <hip/hip_runtime.h>
#include <hip/hip_bf16.h>
#include <math.h>

#define NN 100000
#define EE 1600000
#define IN_F 128
#define HH 4
#define DD 32
#define LL 3
#define NB_ 391          // node buckets of 256: ceil(N/256)
#define EPB 4096         // edges per block in bucket hist/partition

typedef __bf16 bf16x8 __attribute__((ext_vector_type(8)));
typedef float f32x4 __attribute__((ext_vector_type(4)));

static __device__ __forceinline__ unsigned short f2bf(float x) {
    __hip_bfloat16 b = __float2bfloat16(x);
    return *reinterpret_cast<unsigned short*>(&b);
}

// W [l][k][n] fp32 -> wt [l][n][k] bf16 (B-operand layout for MFMA)
__global__ void wt_kernel(const float* __restrict__ Ws,
                          unsigned short* __restrict__ wt) {
    const int i = blockIdx.x * blockDim.x + threadIdx.x;   // L*128*128
    if (i >= LL * IN_F * IN_F) return;
    const int l = i >> 14, r = i & 16383;
    const int n = r >> 7, k = r & 127;
    wt[i] = f2bf(Ws[(l << 14) + k * IN_F + n]);
}

// ---------------------------------------------------------------------------
// MFMA GEMM: ft = x @ W (bf16 in, fp32 acc), fused el/er dots from fp32 acc.
// F32A=true: A operand is fp32 (layer 0 reads h directly, converts in-reg —
// bit-identical f2bf RNE to the old convert_h pass, which is now deleted).
// ---------------------------------------------------------------------------
template <bool F32A>
__global__ __launch_bounds__(256) void gemm_mfma_kernel(
    const void* __restrict__ a_src,
    const unsigned short* __restrict__ wt,    // [128 n][128 k] bf16
    const float* __restrict__ al,
    const float* __restrict__ ar,
    unsigned short* __restrict__ ft_bf,
    float* __restrict__ el,
    float* __restrict__ er) {
    const int wave = (blockIdx.x * blockDim.x + threadIdx.x) >> 6;
    const int lane = threadIdx.x & 63;
    const int base = wave * 16;
    if (base >= NN) return;
    const int c = lane & 15;
    const int quad = lane >> 4;

    const int arow = min(base + c, NN - 1);
    bf16x8 a[4];
    if (F32A) {
        const float4* xp = (const float4*)((const float*)a_src + (size_t)arow * IN_F);
#pragma unroll
        for (int kc = 0; kc < 4; ++kc) {
            const float4 lo = xp[(kc * 4 + quad) * 2];
            const float4 hi = xp[(kc * 4 + quad) * 2 + 1];
            union { unsigned short us[8]; bf16x8 v; } u;
            u.us[0] = f2bf(lo.x); u.us[1] = f2bf(lo.y);
            u.us[2] = f2bf(lo.z); u.us[3] = f2bf(lo.w);
            u.us[4] = f2bf(hi.x); u.us[5] = f2bf(hi.y);
            u.us[6] = f2bf(hi.z); u.us[7] = f2bf(hi.w);
            a[kc] = u.v;
        }
    } else {
        const bf16x8* ap = (const bf16x8*)((const unsigned short*)a_src + (size_t)arow * IN_F);
#pragma unroll
        for (int kc = 0; kc < 4; ++kc) a[kc] = ap[kc * 4 + quad];
    }

    f32x4 acc[8];
#pragma unroll
    for (int nt = 0; nt < 8; ++nt) {
        const bf16x8* bp = (const bf16x8*)(wt + (size_t)(nt * 16 + c) * IN_F);
        f32x4 d = {0.f, 0.f, 0.f, 0.f};
#pragma unroll
        for (int kc = 0; kc < 4; ++kc)
            d = __builtin_amdgcn_mfma_f32_16x16x32_bf16(a[kc], bp[kc * 4 + quad], d, 0, 0, 0);
        acc[nt] = d;
    }

    // ft store (bf16)
#pragma unroll
    for (int r = 0; r < 4; ++r) {
        const int n = base + quad * 4 + r;
        if (n < NN) {
#pragma unroll
            for (int nt = 0; nt < 8; ++nt)
                ft_bf[(size_t)n * IN_F + nt * 16 + c] = f2bf(acc[nt][r]);
        }
    }

    // attention dots from fp32 acc: head h covers tiles 2h, 2h+1
#pragma unroll
    for (int h = 0; h < 4; ++h) {
        float pl[4], pr[4];
#pragma unroll
        for (int r = 0; r < 4; ++r) {
            const float a0 = acc[2 * h][r], a1 = acc[2 * h + 1][r];
            pl[r] = a0 * al[h * 32 + c] + a1 * al[h * 32 + 16 + c];
            pr[r] = a0 * ar[h * 32 + c] + a1 * ar[h * 32 + 16 + c];
        }
#pragma unroll
        for (int off = 8; off >= 1; off >>= 1) {
#pragma unroll
            for (int r = 0; r < 4; ++r) {
                pl[r] += __shfl_xor(pl[r], off);
                pr[r] += __shfl_xor(pr[r], off);
            }
        }
        if (c == 0) {
#pragma unroll
            for (int r = 0; r < 4; ++r) {
                const int n = base + quad * 4 + r;
                if (n < NN) {
                    el[n * HH + h] = pl[r];
                    er[n * HH + h] = pr[r];
                }
            }
        }
    }
}

// ---------------------------------------------------------------------------
// CSR build, two-pass bucket radix by dst>>8 (391 buckets of 256 nodes).
// ---------------------------------------------------------------------------

// per-block LDS histogram of bucket ids -> global bucket totals
__global__ void bucket_hist_kernel(const int* __restrict__ dst,
                                   int* __restrict__ tot) {
    __shared__ int l[NB_];
    for (int b = threadIdx.x; b < NB_; b += 256) l[b] = 0;
    __syncthreads();
    const int e0 = blockIdx.x * EPB;
    const int e1 = min(e0 + EPB, EE);
    for (int e = e0 + threadIdx.x; e < e1; e += 256)
        atomicAdd(&l[dst[e] >> 8], 1);
    __syncthreads();
    for (int b = threadIdx.x; b < NB_; b += 256)
        if (l[b]) atomicAdd(&tot[b], l[b]);
}

// exclusive scan of 391 bucket totals; writes base (NB_+1) and cursor copy
__global__ void bucket_scan_kernel(const int* __restrict__ tot,
                                   int* __restrict__ base,
                                   int* __restrict__ cur) {
    __shared__ int tmp[512];
    const int tid = threadIdx.x;
    int v = (tid < NB_) ? tot[tid] : 0;
    tmp[tid] = v;
    __syncthreads();
    for (int off = 1; off < 512; off <<= 1) {
        int t = (tid >= off) ? tmp[tid - off] : 0;
        __syncthreads();
        if (tid >= off) tmp[tid] += t;
        __syncthreads();
    }
    if (tid < NB_) {
        const int excl = tmp[tid] - v;
        base[tid] = excl;
        cur[tid] = excl;
    }
    if (tid == 0) base[NB_] = EE;
}

// partition edges into buckets: one atomic per (block,bucket) to reserve a
// range, then append packed (dstLow<<17 | src).
__global__ void partition_kernel(const int* __restrict__ src,
                                 const int* __restrict__ dst,
                                 int* __restrict__ cur,
                                 int* __restrict__ bkt) {
    __shared__ int lcnt[NB_];
    __shared__ int lbase[NB_];
    const int tid = threadIdx.x;
    const int e0 = blockIdx.x * EPB;
    const int e1 = min(e0 + EPB, EE);
    for (int b = tid; b < NB_; b += 256) lcnt[b] = 0;
    __syncthreads();
    for (int e = e0 + tid; e < e1; e += 256)
        atomicAdd(&lcnt[dst[e] >> 8], 1);
    __syncthreads();
    for (int b = tid; b < NB_; b += 256) {
        const int c = lcnt[b];
        lbase[b] = c ? atomicAdd(&cur[b], c) : 0;
        lcnt[b] = 0;
    }
    __syncthreads();
    for (int e = e0 + tid; e < e1; e += 256) {
        const int d = dst[e];
        const int b = d >> 8;
        const int idx = atomicAdd(&lcnt[b], 1);
        bkt[lbase[b] + idx] = ((d & 255) << 17) | src[e];
    }
}

// within-bucket sort: LDS count+scan over 256 local nodes emits cnt[] and
// row_start[] directly; final ssrc scatter lands in a contiguous window.
// (No per-node src sort: round-4 measured it +104 us cost for -19 us gain.)
__global__ void bucket_sort_kernel(const int* __restrict__ bkt,
                                   const int* __restrict__ base,
                                   int* __restrict__ cnt,
                                   int* __restrict__ row_start,
                                   int* __restrict__ ssrc) {
    __shared__ int lcnt[256];
    __shared__ int loff[256];
    const int tid = threadIdx.x;
    const int b = blockIdx.x;
    const int s0 = base[b], s1 = base[b + 1];
    lcnt[tid] = 0;
    __syncthreads();
    for (int p = s0 + tid; p < s1; p += 256)
        atomicAdd(&lcnt[bkt[p] >> 17], 1);
    __syncthreads();
    const int v = lcnt[tid];
    loff[tid] = v;
    __syncthreads();
    for (int off = 1; off < 256; off <<= 1) {
        int t = (tid >= off) ? loff[tid - off] : 0;
        __syncthreads();
        if (tid >= off) loff[tid] += t;
        __syncthreads();
    }
    const int excl = loff[tid] - v;          // exclusive local offset
    const int n = b * 256 + tid;
    if (n < NN) {
        cnt[n] = v;
        row_start[n] = s0 + excl;
    }
    __syncthreads();
    loff[tid] = excl;
    lcnt[tid] = 0;
    __syncthreads();
    for (int p = s0 + tid; p < s1; p += 256) {
        const int w = bkt[p];
        const int dl = w >> 17;
        const int idx = atomicAdd(&lcnt[dl], 1);
        ssrc[s0 + loff[dl] + idx] = w & 0x1FFFF;
    }
}

// ---------------------------------------------------------------------------
// Fused aggregation: one wave per dst node; the two wave halves process two
// edges of the SAME node concurrently, each lane covering 4 features via
// dwordx2 gathers.  Main loop unrolled to 8 edges (4 row-gathers in flight
// per half) to cover L2-miss latency.
// ---------------------------------------------------------------------------
__global__ void aggregate_kernel(const unsigned int* __restrict__ ftw,
                                 const float* __restrict__ el,
                                 const float* __restrict__ er,
                                 const float* __restrict__ xin,
                                 const float* __restrict__ bias,
                                 const int* __restrict__ row_start,
                                 const int* __restrict__ cnt,
                                 const int* __restrict__ ssrc,
                                 float* __restrict__ out,
                                 unsigned short* __restrict__ out_bf,
                                 float* __restrict__ den_arr) {
    const int n = (blockIdx.x * blockDim.x + threadIdx.x) >> 6;
    const int lane = threadIdx.x & 63;
    if (n >= NN) return;
    const int half = lane >> 5;          // 0: even edges, 1: odd edges
    const int l31 = lane & 31;           // features 4*l31 .. 4*l31+3
    const int h = l31 >> 3;              // head

    const float ern = er[n * HH + h];
    const int beg = row_start[n];
    const int end = beg + cnt[n];

    float acc0 = 0.f, acc1 = 0.f, acc2 = 0.f, acc3 = 0.f, den = 0.f;
    const uint2* ft2 = (const uint2*)ftw;   // row = 32 x uint2 (128 bf16)

    int p = beg;
    for (; p + 8 <= end; p += 8) {
        const int sA = ssrc[p + half];
        const int sB = ssrc[p + 2 + half];
        const int sC = ssrc[p + 4 + half];
        const int sD = ssrc[p + 6 + half];
        float evA = el[sA * HH + h] + ern;
        float evB = el[sB * HH + h] + ern;
        float evC = el[sC * HH + h] + ern;
        float evD = el[sD * HH + h] + ern;
        const uint2 wA = ft2[(size_t)sA * 32 + l31];
        const uint2 wB = ft2[(size_t)sB * 32 + l31];
        const uint2 wC = ft2[(size_t)sC * 32 + l31];
        const uint2 wD = ft2[(size_t)sD * 32 + l31];
        evA = evA > 0.f ? evA : 0.2f * evA;
        evB = evB > 0.f ? evB : 0.2f * evB;
        evC = evC > 0.f ? evC : 0.2f * evC;
        evD = evD > 0.f ? evD : 0.2f * evD;
        const float eA = __expf(evA);
        const float eB = __expf(evB);
        const float eC = __expf(evC);
        const float eD = __expf(evD);
        den += (eA + eB) + (eC + eD);
        acc0 = fmaf(eA, __uint_as_float(wA.x << 16), acc0);
        acc1 = fmaf(eA, __uint_as_float(wA.x & 0xffff0000u), acc1);
        acc2 = fmaf(eA, __uint_as_float(wA.y << 16), acc2);
        acc3 = fmaf(eA, __uint_as_float(wA.y & 0xffff0000u), acc3);
        acc0 = fmaf(eB, __uint_as_float(wB.x << 16), acc0);
        acc1 = fmaf(eB, __uint_as_float(wB.x & 0xffff0000u), acc1);
        acc2 = fmaf(eB, __uint_as_float(wB.y << 16), acc2);
        acc3 = fmaf(eB, __uint_as_float(wB.y & 0xffff0000u), acc3);
        acc0 = fmaf(eC, __uint_as_float(wC.x << 16), acc0);
        acc1 = fmaf(eC, __uint_as_float(wC.x & 0xffff0000u), acc1);
        acc2 = fmaf(eC, __uint_as_float(wC.y << 16), acc2);
        acc3 = fmaf(eC, __uint_as_float(wC.y & 0xffff0000u), acc3);
        acc0 = fmaf(eD, __uint_as_float(wD.x << 16), acc0);
        acc1 = fmaf(eD, __uint_as_float(wD.x & 0xffff0000u), acc1);
        acc2 = fmaf(eD, __uint_as_float(wD.y << 16), acc2);
        acc3 = fmaf(eD, __uint_as_float(wD.y & 0xffff0000u), acc3);
    }
    for (; p + 4 <= end; p += 4) {
        const int sA = ssrc[p + half];
        const int sB = ssrc[p + 2 + half];
        float evA = el[sA * HH + h] + ern;
        float evB = el[sB * HH + h] + ern;
        const uint2 wA = ft2[(size_t)sA * 32 + l31];
        const uint2 wB = ft2[(size_t)sB * 32 + l31];
        evA = evA > 0.f ? evA : 0.2f * evA;
        evB = evB > 0.f ? evB : 0.2f * evB;
        const float eA = __expf(evA);
        const float eB = __expf(evB);
        den += eA + eB;
        acc0 = fmaf(eA, __uint_as_float(wA.x << 16), acc0);
        acc1 = fmaf(eA, __uint_as_float(wA.x & 0xffff0000u), acc1);
        acc2 = fmaf(eA, __uint_as_float(wA.y << 16), acc2);
        acc3 = fmaf(eA, __uint_as_float(wA.y & 0xffff0000u), acc3);
        acc0 = fmaf(eB, __uint_as_float(wB.x << 16), acc0);
        acc1 = fmaf(eB, __uint_as_float(wB.x & 0xffff0000u), acc1);
        acc2 = fmaf(eB, __uint_as_float(wB.y << 16), acc2);
        acc3 = fmaf(eB, __uint_as_float(wB.y & 0xffff0000u), acc3);
    }
    for (; p < end; p += 2) {
        const bool valid = (p + half) < end;
        // invalid lanes replay a valid row (beg < end here) with ee=0 so no
        // garbage bf16 bits (possible inf/nan) enter an fma.
        const int s = ssrc[valid ? p + half : beg];
        float ev = el[s * HH + h] + ern;
        const uint2 w = ft2[(size_t)s * 32 + l31];
        ev = ev > 0.f ? ev : 0.2f * ev;
        const float e1 = valid ? __expf(ev) : 0.f;
        den += e1;
        acc0 = fmaf(e1, __uint_as_float(w.x << 16), acc0);
        acc1 = fmaf(e1, __uint_as_float(w.x & 0xffff0000u), acc1);
        acc2 = fmaf(e1, __uint_as_float(w.y << 16), acc2);
        acc3 = fmaf(e1, __uint_as_float(w.y & 0xffff0000u), acc3);
    }

    // combine the two halves
    den  += __shfl_xor(den, 32);
    acc0 += __shfl_xor(acc0, 32);
    acc1 += __shfl_xor(acc1, 32);
    acc2 += __shfl_xor(acc2, 32);
    acc3 += __shfl_xor(acc3, 32);

    if (lane < 32) {
        if ((l31 & 7) == 0) den_arr[n * HH + h] = den;
        const float inv = 1.f / fmaxf(den, 1e-9f);
        const float4 xi = ((const float4*)xin)[(size_t)n * 32 + l31];
        const float4 bb = ((const float4*)bias)[l31];
        float v0 = acc0 * inv + xi.x + bb.x;
        float v1 = acc1 * inv + xi.y + bb.y;
        float v2 = acc2 * inv + xi.z + bb.z;
        float v3 = acc3 * inv + xi.w + bb.w;
        v0 = v0 > 0.f ? v0 : __expf(v0) - 1.f;
        v1 = v1 > 0.f ? v1 : __expf(v1) - 1.f;
        v2 = v2 > 0.f ? v2 : __expf(v2) - 1.f;
        v3 = v3 > 0.f ? v3 : __expf(v3) - 1.f;
        ((float4*)out)[(size_t)n * 32 + l31] = make_float4(v0, v1, v2, v3);
        ushort4 ob;
        ob.x = f2bf(v0); ob.y = f2bf(v1); ob.z = f2bf(v2); ob.w = f2bf(v3);
        ((ushort4*)out_bf)[(size_t)n * 32 + l31] = ob;
    }
}

// ---------------------------------------------------------------------------
// a[e,h] = exp(leaky(el[src]+er[dst])) / den[dst]  (bit-identical __expf)
// ---------------------------------------------------------------------------
__global__ void attn_out_kernel(const int* __restrict__ src,
                                const int* __restrict__ dst,
                                const float* __restrict__ el,
                                const float* __restrict__ er,
                                const float* __restrict__ den,
                                float* __restrict__ a_out) {
    const int e = blockIdx.x * blockDim.x + threadIdx.x;
    if (e >= EE) return;
    const int s = src[e], d = dst[e];
    const float4 l4 = ((const float4*)el)[s];
    const float4 r4 = ((const float4*)er)[d];
    const float4 dn = ((const float4*)den)[d];
    float v[4] = {l4.x + r4.x, l4.y + r4.y, l4.z + r4.z, l4.w + r4.w};
    float dv[4] = {dn.x, dn.y, dn.z, dn.w};
    float4 o;
    float* op = &o.x;
#pragma unroll
    for (int hh = 0; hh < 4; ++hh) {
        float t = v[hh] > 0.f ? v[hh] : 0.2f * v[hh];
        op[hh] = __expf(t) / fmaxf(dv[hh], 1e-9f);
    }
    ((float4*)a_out)[e] = o;
}

extern "C" void kernel_launch(void* const* d_in, const int* in_sizes, int n_in,
                              void* d_out, int out_size, void* d_ws, size_t ws_size,
                              hipStream_t stream) {
    const float* h    = (const float*)d_in[0];
    const int*   src  = (const int*)  d_in[1];
    const int*   dst  = (const int*)  d_in[2];
    const float* Ws   = (const float*)d_in[3];
    const float* al   = (const float*)d_in[4];
    const float* ar   = (const float*)d_in[5];
    const float* bias = (const float*)d_in[6];

    float* out_x = (float*)d_out;                         // [N,128] fp32
    float* out_a = out_x + (size_t)NN * IN_F;             // [E,4] fp32
    // x_bf (N*128 bf16 = 25.6 MB) aliases the out_a region (E*4 f32 = 25.6 MB):
    // it holds aggregate's bf16 outputs (layer 1/2 GEMM inputs) during the
    // layer loop; attn_out overwrites it at the end.
    unsigned short* x_bf = (unsigned short*)out_a;

    char* ws = (char*)d_ws;
    unsigned short* ft_bf = (unsigned short*)ws;              // N*128 bf16
    float* bufA = (float*)(ft_bf + (size_t)NN * IN_F);        // N*128 f32
    float* el   = bufA + (size_t)NN * IN_F;                   // N*4
    float* er   = el + (size_t)NN * HH;                       // N*4
    float* den  = er + (size_t)NN * HH;                       // N*4
    int*   cnt        = (int*)(den + (size_t)NN * HH);        // N
    int*   row_start  = cnt + NN;                             // N
    int*   bucket_tot = row_start + NN;                       // 512 (NB_ used)
    int*   bucket_base= bucket_tot + 512;                     // 512 (NB_+1 used)
    int*   bucket_cur = bucket_base + 512;                    // 512 (NB_ used)
    int*   ssrc       = bucket_cur + 512;                     // E
    unsigned short* wt = (unsigned short*)(ssrc + EE);        // 3*128*128 bf16
    // bkt (E ints, CSR-build scratch only) aliases bufA: bufA is first
    // written by layer-0 aggregate, strictly after bucket_sort has consumed bkt.
    int* bkt = (int*)bufA;

    // ---- one-time conversions + CSR build (identical every call) ----
    wt_kernel<<<(LL * IN_F * IN_F + 255) / 256, 256, 0, stream>>>(Ws, wt);

    hipMemsetAsync(bucket_tot, 0, 512 * sizeof(int), stream);
    const int ebks = (EE + EPB - 1) / EPB;   // 391
    bucket_hist_kernel<<<ebks, 256, 0, stream>>>(dst, bucket_tot);
    bucket_scan_kernel<<<1, 512, 0, stream>>>(bucket_tot, bucket_base, bucket_cur);
    partition_kernel<<<ebks, 256, 0, stream>>>(src, dst, bucket_cur, bkt);
    bucket_sort_kernel<<<NB_, 256, 0, stream>>>(bkt, bucket_base, cnt, row_start, ssrc);

    // layer schedule: L0: h->bufA, L1: bufA->out_x, L2: out_x->out_x
    const float* xin[LL]  = {h, bufA, out_x};
    float*       xout[LL] = {bufA, out_x, out_x};
    const int gemm_blocks = ((NN + 15) / 16 + 3) / 4;   // waves of 16 nodes, 4/block

    for (int i = 0; i < LL; ++i) {
        const float* all_ = al + (size_t)i * HH * DD;
        const float* arl = ar + (size_t)i * HH * DD;
        const float* bl  = bias + (size_t)i * HH * DD;

        if (i == 0) {
            gemm_mfma_kernel<true><<<gemm_blocks, 256, 0, stream>>>(
                (const void*)h, wt + (size_t)i * IN_F * IN_F, all_, arl, ft_bf, el, er);
        } else {
            gemm_mfma_kernel<false><<<gemm_blocks, 256, 0, stream>>>(
                (const void*)x_bf, wt + (size_t)i * IN_F * IN_F, all_, arl, ft_bf, el, er);
        }
        aggregate_kernel<<<(NN + 3) / 4, 256, 0, stream>>>(
            (const unsigned int*)ft_bf, el, er, xin[i], bl, row_start, cnt, ssrc,
            xout[i], x_bf, den);
    }
    attn_out_kernel<<<(EE + 255) / 256, 256, 0, stream>>>(src, dst, el, er, den, out_a);
}